// Round 1
// baseline (428.919 us; speedup 1.0000x reference)
//
#include <hip/hip_runtime.h>

#define NG 16
#define NC 4
#define BPB 8      // batch items per block
#define TSTEPS 8

__device__ __forceinline__ float4 lrelu4(float4 v) {
    float4 r;
    r.x = v.x > 0.f ? v.x : 0.1f * v.x;
    r.y = v.y > 0.f ? v.y : 0.1f * v.y;
    r.z = v.z > 0.f ? v.z : 0.1f * v.z;
    r.w = v.w > 0.f ? v.w : 0.1f * v.w;
    return r;
}

__device__ __forceinline__ void fma8(float w, const float4& s0, const float4& s1,
                                     float4& a0, float4& a1) {
    a0.x = fmaf(w, s0.x, a0.x);
    a0.y = fmaf(w, s0.y, a0.y);
    a0.z = fmaf(w, s0.z, a0.z);
    a0.w = fmaf(w, s0.w, a0.w);
    a1.x = fmaf(w, s1.x, a1.x);
    a1.y = fmaf(w, s1.y, a1.y);
    a1.z = fmaf(w, s1.z, a1.z);
    a1.w = fmaf(w, s1.w, a1.w);
}

// Build W_t[pix][c][u][v][o] as float4 over o, with OOB (u,v) pre-zeroed.
// Original W layout: [y][x][o][c][u][v]  (flat: pix*400 + o*100 + c*25 + u*5 + v)
__global__ void wt_transpose(const float* __restrict__ W, float4* __restrict__ Wt) {
    int tid = blockIdx.x * 256 + threadIdx.x;   // 0 .. 25599
    if (tid >= 256 * 100) return;
    int pix = tid / 100;
    int r   = tid - pix * 100;
    int c   = r / 25;
    int uv  = r - c * 25;
    int u   = uv / 5;
    int v   = uv - u * 5;
    int y = pix >> 4, x = pix & 15;
    float4 w = make_float4(0.f, 0.f, 0.f, 0.f);
    if ((unsigned)(y + u - 2) < 16u && (unsigned)(x + v - 2) < 16u) {
        int base = pix * 400 + c * 25 + uv;
        w.x = W[base];
        w.y = W[base + 100];
        w.z = W[base + 200];
        w.w = W[base + 300];
    }
    Wt[tid] = w;   // layout: pix*100 + c*25 + u*5 + v
}

// LDS layout: sm[buf][c][y][x][8 floats] ; the 8 floats per pixel are two 16B
// slots (b0-3, b4-7). Physical slot = logical_slot ^ ((x>>2)&1) so that a
// wave's ds_read_b128 across 16 x-positions hits 8 distinct bank-quads
// (all 32 banks) instead of 4.
template<bool USE_WT>
__global__ __launch_bounds__(256, 2)
void reservoir_kernel(const float* __restrict__ X, const float* __restrict__ W,
                      const float4* __restrict__ Wt, float* __restrict__ out,
                      int batch) {
    __shared__ float sm[2 * NC * NG * NG * BPB];   // 65536 B
    float4* smv = reinterpret_cast<float4*>(sm);

    const int tid = threadIdx.x;        // == pixel index, 256 threads
    const int y = tid >> 4;
    const int x = tid & 15;
    const long itemBase = (long)blockIdx.x * BPB;

    // ---- init: load x (first 784 of 1024, rest zero) into buf 0 ----
    for (int b = 0; b < BPB; ++b) {
        long item = itemBase + b;
        const float* xr = X + item * 784;
        const int g = b >> 2, j = b & 3;
        #pragma unroll
        for (int k = 0; k < 4; ++k) {
            int idx = tid + k * 256;
            float v = 0.f;
            if (idx < 784 && item < batch) v = xr[idx];
            int c   = idx >> 8;
            int rem = idx & 255;
            int yy  = rem >> 4;
            int xx  = rem & 15;
            int phys = g ^ ((xx >> 2) & 1);
            sm[(((c * NG + yy) * NG + xx) * BPB) + phys * 4 + j] = v;
        }
    }
    __syncthreads();

    // per-v precompute: clamped column -> float4 offset within a row (incl. swizzle)
    int xofs[5];
    #pragma unroll
    for (int v = 0; v < 5; ++v) {
        int xv = x + v - 2;
        xv = xv < 0 ? 0 : (xv > 15 ? 15 : xv);
        xofs[v] = xv * 2 + ((xv >> 2) & 1);
    }
    const int sbx = (x >> 2) & 1;
    const int wbase_t = tid * 100;   // float4 index into Wt
    const int wbase_s = tid * 400;   // float index into W

    float maskv[5];
    if constexpr (!USE_WT) {
        #pragma unroll
        for (int v = 0; v < 5; ++v)
            maskv[v] = ((unsigned)(x + v - 2) < 16u) ? 1.f : 0.f;
    }

    #pragma unroll 1
    for (int t = 0; t < TSTEPS; ++t) {
        const int rbuf = t & 1;
        float4 a00 = {0,0,0,0}, a01 = {0,0,0,0};
        float4 a10 = {0,0,0,0}, a11 = {0,0,0,0};
        float4 a20 = {0,0,0,0}, a21 = {0,0,0,0};
        float4 a30 = {0,0,0,0}, a31 = {0,0,0,0};

        #pragma unroll 1
        for (int c = 0; c < NC; ++c) {
            #pragma unroll
            for (int u = 0; u < 5; ++u) {
                int yy = y + u - 2;
                yy = yy < 0 ? 0 : (yy > 15 ? 15 : yy);
                const int rowb = ((rbuf * NC + c) * NG + yy) * NG * 2;  // float4 idx
                float4 w[5];
                if constexpr (USE_WT) {
                    const float4* wr = Wt + wbase_t + c * 25 + u * 5;
                    #pragma unroll
                    for (int v = 0; v < 5; ++v) w[v] = wr[v];
                } else {
                    const float rm = ((unsigned)(y + u - 2) < 16u) ? 1.f : 0.f;
                    const float* wr = W + wbase_s + c * 25 + u * 5;
                    #pragma unroll
                    for (int v = 0; v < 5; ++v) {
                        float m = rm * maskv[v];
                        w[v].x = wr[v]       * m;
                        w[v].y = wr[v + 100] * m;
                        w[v].z = wr[v + 200] * m;
                        w[v].w = wr[v + 300] * m;
                    }
                }
                #pragma unroll
                for (int v = 0; v < 5; ++v) {
                    const int f4i = rowb + xofs[v];
                    const float4 s0 = smv[f4i];       // b0-3
                    const float4 s1 = smv[f4i ^ 1];   // b4-7 (other slot)
                    fma8(w[v].x, s0, s1, a00, a01);
                    fma8(w[v].y, s0, s1, a10, a11);
                    fma8(w[v].z, s0, s1, a20, a21);
                    fma8(w[v].w, s0, s1, a30, a31);
                }
            }
        }

        a00 = lrelu4(a00); a01 = lrelu4(a01);
        a10 = lrelu4(a10); a11 = lrelu4(a11);
        a20 = lrelu4(a20); a21 = lrelu4(a21);
        a30 = lrelu4(a30); a31 = lrelu4(a31);

        if (t < TSTEPS - 1) {
            const int wb = rbuf ^ 1;
            int b0 = ((wb * NC + 0) * NG + y) * NG * 2 + x * 2;
            smv[b0 + sbx] = a00; smv[b0 + (sbx ^ 1)] = a01;
            int b1 = ((wb * NC + 1) * NG + y) * NG * 2 + x * 2;
            smv[b1 + sbx] = a10; smv[b1 + (sbx ^ 1)] = a11;
            int b2 = ((wb * NC + 2) * NG + y) * NG * 2 + x * 2;
            smv[b2 + sbx] = a20; smv[b2 + (sbx ^ 1)] = a21;
            int b3 = ((wb * NC + 3) * NG + y) * NG * 2 + x * 2;
            smv[b3 + sbx] = a30; smv[b3 + (sbx ^ 1)] = a31;
            __syncthreads();
        } else {
            // pool over channels directly from registers, mean = sum * 0.25
            float4 p0, p1;
            p0.x = (a00.x + a10.x + a20.x + a30.x) * 0.25f;
            p0.y = (a00.y + a10.y + a20.y + a30.y) * 0.25f;
            p0.z = (a00.z + a10.z + a20.z + a30.z) * 0.25f;
            p0.w = (a00.w + a10.w + a20.w + a30.w) * 0.25f;
            p1.x = (a01.x + a11.x + a21.x + a31.x) * 0.25f;
            p1.y = (a01.y + a11.y + a21.y + a31.y) * 0.25f;
            p1.z = (a01.z + a11.z + a21.z + a31.z) * 0.25f;
            p1.w = (a01.w + a11.w + a21.w + a31.w) * 0.25f;
            long ob = itemBase * 256 + tid;
            if (itemBase + 0 < batch) out[ob + 0 * 256] = p0.x;
            if (itemBase + 1 < batch) out[ob + 1 * 256] = p0.y;
            if (itemBase + 2 < batch) out[ob + 2 * 256] = p0.z;
            if (itemBase + 3 < batch) out[ob + 3 * 256] = p0.w;
            if (itemBase + 4 < batch) out[ob + 4 * 256] = p1.x;
            if (itemBase + 5 < batch) out[ob + 5 * 256] = p1.y;
            if (itemBase + 6 < batch) out[ob + 6 * 256] = p1.z;
            if (itemBase + 7 < batch) out[ob + 7 * 256] = p1.w;
        }
    }
}

extern "C" void kernel_launch(void* const* d_in, const int* in_sizes, int n_in,
                              void* d_out, int out_size, void* d_ws, size_t ws_size,
                              hipStream_t stream) {
    const float* X = (const float*)d_in[0];
    const float* W = (const float*)d_in[1];
    float* out = (float*)d_out;
    const int batch = in_sizes[0] / 784;            // 8192
    const int blocks = (batch + BPB - 1) / BPB;     // 1024

    const size_t wt_bytes = (size_t)256 * 100 * sizeof(float4);  // 409600
    if (ws_size >= wt_bytes) {
        wt_transpose<<<100, 256, 0, stream>>>(W, (float4*)d_ws);
        reservoir_kernel<true><<<blocks, 256, 0, stream>>>(
            X, W, (const float4*)d_ws, out, batch);
    } else {
        reservoir_kernel<false><<<blocks, 256, 0, stream>>>(
            X, W, nullptr, out, batch);
    }
}